// Round 11
// baseline (361.285 us; speedup 1.0000x reference)
//
#include <hip/hip_runtime.h>
#include <cstdint>

// PointTransformerLayer, MI355X. Folded-weight formulation:
//   M  = Wt2@Wt1 (64x3)          delta = relu(M . rel)
//   G  = Wg2@Wg1 (64x64)         g = relu(Gphi[n] - Gpsi[idx] + G.delta)
//   GW1= G@Wlin[0:64], GW2 = G@Wlin[64:128], alpha = Wlin[128:192] @ f
// KNN v4 (R11): lane-parallel top-8 in regs (med3 sorted-insert), wave
//   merge via DPP min-reduce (6 v_min+DPP, VALU pipe) + readlane bcast --
//   replaces the shfl_xor butterfly whose 24x6 dependent ds_swizzles cost
//   ~5000 cyc/wave (R10 arithmetic: 103 cyc/step wall vs ~45 instr).
//   Split into 4 quarter-launches so any non-knn kernel >= ~31us must
//   surface in top-5 (attribution of the opaque ~185us non-knn block).
//   Then numpy-fp32-bit-exact re-rank of 24 survivors (stable ties).

#define NPT 8192
typedef unsigned long long u64;
typedef unsigned int u32;
typedef unsigned short u16;
typedef __attribute__((ext_vector_type(8))) short bf8_t;  // 8 bf16 (4 VGPR)
typedef __attribute__((ext_vector_type(4))) float f32x4;

__device__ __forceinline__ u16 f2bf(float x) {  // round-half-up bf16
  return (u16)((__float_as_uint(x) + 0x8000u) >> 16);
}
__device__ __forceinline__ u32 pkbf(float lo, float hi) {
  return (u32)f2bf(lo) | ((u32)f2bf(hi) << 16);
}
__device__ __forceinline__ float bf2f(u16 v) {
  return __uint_as_float((u32)v << 16);
}
__device__ __forceinline__ u32 med3u(u32 a, u32 b, u32 c) {
  u32 d;
  asm("v_med3_u32 %0, %1, %2, %3" : "=v"(d) : "v"(a), "v"(b), "v"(c));
  return d;
}
// full-wave u32 min via DPP (VALU pipe, no ds_swizzle); uniform result.
// Invalid-source lanes keep `old` (bound_ctrl=false) -> min unaffected.
__device__ __forceinline__ u32 wave_min_u32(u32 v) {
  u32 t;
  t = (u32)__builtin_amdgcn_update_dpp((int)v, (int)v, 0x111, 0xF, 0xF, false); v = min(v, t); // row_shr:1
  t = (u32)__builtin_amdgcn_update_dpp((int)v, (int)v, 0x112, 0xF, 0xF, false); v = min(v, t); // row_shr:2
  t = (u32)__builtin_amdgcn_update_dpp((int)v, (int)v, 0x114, 0xF, 0xF, false); v = min(v, t); // row_shr:4
  t = (u32)__builtin_amdgcn_update_dpp((int)v, (int)v, 0x118, 0xF, 0xF, false); v = min(v, t); // row_shr:8
  t = (u32)__builtin_amdgcn_update_dpp((int)v, (int)v, 0x142, 0xF, 0xF, false); v = min(v, t); // row_bcast:15
  t = (u32)__builtin_amdgcn_update_dpp((int)v, (int)v, 0x143, 0xF, 0xF, false); v = min(v, t); // row_bcast:31
  return (u32)__builtin_amdgcn_readlane((int)v, 63);  // SGPR-uniform
}

// ---------- fold1: G = Wg2@Wg1 (64x64); M = Wt2@Wt1 (64x3, row + colT) ----
__global__ __launch_bounds__(256) void fold1_k(
    const float* __restrict__ wg1, const float* __restrict__ wg2,
    const float* __restrict__ wt1, const float* __restrict__ wt2,
    float* __restrict__ G, float* __restrict__ Mrow, float* __restrict__ McT) {
  int t = blockIdx.x * 256 + threadIdx.x;
  if (t < 4096) {
    int o = t >> 6, c = t & 63;
    float acc = 0.f;
    for (int cp = 0; cp < 64; ++cp) acc = fmaf(wg2[o * 64 + cp], wg1[cp * 64 + c], acc);
    G[o * 64 + c] = acc;
  } else if (t < 4096 + 192) {
    int i = t - 4096;
    int o = i / 3, j = i - o * 3;
    float acc = 0.f;
    for (int c = 0; c < 64; ++c) acc = fmaf(wt2[o * 64 + c], wt1[c * 3 + j], acc);
    Mrow[o * 3 + j] = acc;
    McT[j * 64 + o] = acc;
  }
}

// ---------- fold2: wcomb + GF (G prepacked as bf16 MFMA A-frags) ----------
__global__ __launch_bounds__(256) void fold2_k(
    const float* __restrict__ G, const float* __restrict__ wl,
    float* __restrict__ wcomb, u16* __restrict__ GF) {
  int t = blockIdx.x * 256 + threadIdx.x;  // 16384
  if (t < 12288) {
    int o = t >> 6, c = t & 63;
    float acc = 0.f;
    if (o < 64) {
      for (int cp = 0; cp < 64; ++cp) acc = fmaf(G[o * 64 + cp], wl[cp * 64 + c], acc);
    } else if (o < 128) {
      for (int cp = 0; cp < 64; ++cp) acc = fmaf(G[(o - 64) * 64 + cp], wl[(64 + cp) * 64 + c], acc);
    } else {
      acc = wl[o * 64 + c];
    }
    wcomb[o * 64 + c] = acc;
  } else if (t < 16384) {
    int i = t - 12288;
    int o = i >> 6, c = i & 63;
    int ot = o >> 4, m = o & 15;
    int kh = c >> 5, q = (c >> 3) & 3, j = c & 7;
    GF[(((ot * 2 + kh) * 64) + (q * 16 + m)) * 8 + j] = f2bf(G[o * 64 + c]);
  }
}

// ---------- pack coords as float4 (x,y,z,sq) with NP-EXACT sq -------------
__global__ __launch_bounds__(256) void pack_k(const float* __restrict__ coords,
                                              float4* __restrict__ pack) {
  int g = blockIdx.x * 256 + threadIdx.x;  // 32768
  int b = g >> 13, n = g & (NPT - 1);
  const float* c = coords + (size_t)b * 3 * NPT;
  float x = c[n], y = c[NPT + n], z = c[2 * NPT + n];
  float sq = __fadd_rn(__fadd_rn(__fmul_rn(x, x), __fmul_rn(y, y)), __fmul_rn(z, z));
  pack[g] = make_float4(x, y, z, sq);
}

// ---------- KNN v4: wave=query, per-lane reg top-8, DPP merge top-24 ------
#define QPB 8
#define CHUNK 1024
#define NQ 32768
__global__ __launch_bounds__(512) void knn_k(const float4* __restrict__ pack,
                                             u32* __restrict__ part, int qbase) {
  __shared__ float4 C[CHUNK];
  int tid = threadIdx.x;
  int w = tid >> 6, lane = tid & 63;
  int query = qbase + blockIdx.x * QPB + w;
  int b = query >> 13, n = query & (NPT - 1);
  const float4* pk = pack + (size_t)b * NPT;
  float4 q = pk[n];
  float qsq = q.w;
  u32 arr[8];
#pragma unroll
  for (int j = 0; j < 8; ++j) arr[j] = 0xFFFFFFFFu;
  for (int c0 = 0; c0 < NPT; c0 += CHUNK) {
    C[tid] = pk[c0 + tid];
    C[tid + 512] = pk[c0 + tid + 512];
    __syncthreads();
#pragma unroll 4
    for (int t = 0; t < CHUNK / 64; ++t) {
      float4 c4 = C[t * 64 + lane];
      float dot = fmaf(q.z, c4.z, fmaf(q.y, c4.y, q.x * c4.x));
      float d2 = fmaxf(fmaf(-2.f, dot, qsq + c4.w), 0.f);
      u32 key = (__float_as_uint(d2) & 0xFFFFE000u) | (u32)(c0 + t * 64 + lane);
      if (key < arr[7]) {  // sorted-insert-drop-max: 1 med3 per slot
        arr[7] = med3u(key, arr[6], arr[7]);
        arr[6] = med3u(key, arr[5], arr[6]);
        arr[5] = med3u(key, arr[4], arr[5]);
        arr[4] = med3u(key, arr[3], arr[4]);
        arr[3] = med3u(key, arr[2], arr[3]);
        arr[2] = med3u(key, arr[1], arr[2]);
        arr[1] = med3u(key, arr[0], arr[1]);
        arr[0] = min(arr[0], key);
      }
    }
    __syncthreads();
  }
  // DPP merge: pop global min 24 times (keys unique -> single owner pops)
  u32 mg = 0xFFFFFFFFu;
#pragma unroll 1
  for (int r = 0; r < 24; ++r) {
    u32 m = wave_min_u32(arr[0]);
    if (lane == r) mg = m;
    if (arr[0] == m) {  // owner pops its sorted head
      arr[0] = arr[1]; arr[1] = arr[2]; arr[2] = arr[3]; arr[3] = arr[4];
      arr[4] = arr[5]; arr[5] = arr[6]; arr[6] = arr[7]; arr[7] = 0xFFFFFFFFu;
    }
  }
  if (lane < 24) part[(size_t)lane * NQ + query] = mg;
}

// ---------- numpy-fp32-bit-exact re-rank of the 24 survivors --------------
__global__ __launch_bounds__(64) void refine_k(const float4* __restrict__ pack,
                                               const u32* __restrict__ part,
                                               int* __restrict__ idxk) {
  int g = blockIdx.x * 64 + threadIdx.x;  // 32768
  int b = g >> 13;
  const float4* pk = pack + (size_t)b * NPT;
  float4 q = pk[g & (NPT - 1)];
  float qx = q.x, qy = q.y, qz = q.z, qs = q.w;
  float bd[16];
  int bi[16];
#pragma unroll
  for (int j = 0; j < 16; ++j) { bd[j] = 1e30f; bi[j] = 0x7FFFFFFF; }
#pragma unroll 4
  for (int j = 0; j < 24; ++j) {
    int m = (int)(part[(size_t)j * NQ + g] & 0x1FFFu);
    float4 pm = pk[m];
    float dot = __fadd_rn(__fadd_rn(__fmul_rn(qx, pm.x), __fmul_rn(qy, pm.y)),
                          __fmul_rn(qz, pm.z));
    float kd = __fsub_rn(__fadd_rn(qs, pm.w), __fmul_rn(2.0f, dot));
    int ki = m;
    if (kd < bd[15] || (kd == bd[15] && ki < bi[15])) {
#pragma unroll
      for (int qq = 0; qq < 16; ++qq) {
        bool cs = (kd < bd[qq]) || (kd == bd[qq] && ki < bi[qq]);
        float td = bd[qq];
        int ti = bi[qq];
        bd[qq] = cs ? kd : td;
        bi[qq] = cs ? ki : ti;
        kd = cs ? td : kd;
        ki = cs ? ti : ki;
      }
    }
  }
#pragma unroll
  for (int j = 0; j < 16; ++j) idxk[(size_t)g * 16 + j] = bi[j];
}

// ---------- feat: featA[P][64]=Gphi fp32; featB[P][128]=Gpsi|alpha bf16 ---
__global__ __launch_bounds__(256) void feat_k(const float* __restrict__ features,
                                              const float* __restrict__ wcomb,
                                              float* __restrict__ featA,
                                              u16* __restrict__ featB) {
  int t = blockIdx.x * 256 + threadIdx.x;  // 65536
  int half = t >> 15;
  int P = t & 32767;
  int b = P >> 13, n = P & (NPT - 1);
  const float* fin = features + (size_t)b * 64 * NPT + n;
  float f[64];
#pragma unroll
  for (int c = 0; c < 64; ++c) f[c] = fin[(size_t)c * NPT];
  const float* W = wcomb + half * 96 * 64;
  for (int r4 = 0; r4 < 24; ++r4) {
    float a0 = 0.f, a1 = 0.f, a2 = 0.f, a3 = 0.f;
    const float* w0 = W + (r4 * 4) * 64;
#pragma unroll
    for (int c = 0; c < 64; ++c) {
      a0 = fmaf(w0[c], f[c], a0);
      a1 = fmaf(w0[64 + c], f[c], a1);
      a2 = fmaf(w0[128 + c], f[c], a2);
      a3 = fmaf(w0[192 + c], f[c], a3);
    }
    int gr = half * 96 + r4 * 4;  // global output row
    if (gr < 64) {
      *(float4*)(featA + (size_t)P * 64 + gr) = make_float4(a0, a1, a2, a3);
    } else {
      uint2 wv = make_uint2(pkbf(a0, a1), pkbf(a2, a3));
      *(uint2*)(featB + (size_t)P * 128 + (gr - 64)) = wv;
    }
  }
}

// ---------- attention v3: MFMA core + uniform-gather read phase -----------
#define SROW 68
__global__ __launch_bounds__(64) void attn_k(
    const float4* __restrict__ pack, const int* __restrict__ idxk,
    const float* __restrict__ featA, const u16* __restrict__ featB,
    const u16* __restrict__ GF, const float* __restrict__ Mrow,
    const float* __restrict__ McT, float* __restrict__ out) {
  __shared__ u16 S16[64 * SROW];
  int l = threadIdx.x;
  int quad = l >> 4, col = l & 15;
  int Pb = blockIdx.x * 4;
  int b = Pb >> 13;
  int nb0 = Pb & (NPT - 1);
  const float4* pkb = pack + (size_t)b * NPT;
  int idxv = idxk[(size_t)Pb * 16 + l];  // lane l = (point l>>4, nbr l&15)
  int mve[4];
#pragma unroll
  for (int t = 0; t < 4; ++t) mve[t] = __shfl(idxv, t * 16 + col);
  float relx[4], rely[4], relz[4];
#pragma unroll
  for (int t = 0; t < 4; ++t) {
    float4 own = pkb[nb0 + t];
    float4 nbr = pkb[mve[t]];
    relx[t] = own.x - nbr.x; rely[t] = own.y - nbr.y; relz[t] = own.z - nbr.z;
  }
  // B-frags: u[k=kh*32+quad*8+j][p'=pt*16+col] = relu(M.rel), bf16
  bf8_t Bf[4][2];
#pragma unroll
  for (int kh = 0; kh < 2; ++kh) {
    const float* mr = Mrow + (kh * 32 + quad * 8) * 3;
    float m_[24];
#pragma unroll
    for (int i6 = 0; i6 < 6; ++i6) {
      float4 v = *(const float4*)(mr + i6 * 4);
      m_[i6 * 4] = v.x; m_[i6 * 4 + 1] = v.y; m_[i6 * 4 + 2] = v.z; m_[i6 * 4 + 3] = v.w;
    }
#pragma unroll
    for (int t = 0; t < 4; ++t) {
      float u_[8];
#pragma unroll
      for (int j = 0; j < 8; ++j)
        u_[j] = fmaxf(fmaf(m_[j * 3 + 2], relz[t],
                           fmaf(m_[j * 3 + 1], rely[t], m_[j * 3] * relx[t])), 0.f);
      union { u32 w[4]; bf8_t v; } ub;
#pragma unroll
      for (int j2 = 0; j2 < 4; ++j2) ub.w[j2] = pkbf(u_[j2 * 2], u_[j2 * 2 + 1]);
      Bf[t][kh] = ub.v;
    }
  }
  // MFMA + fused epilogue -> g (bf16) strip [pair][channel]
  const bf8_t* gfr = (const bf8_t*)GF;
#pragma unroll
  for (int ot = 0; ot < 4; ++ot) {
    bf8_t A0 = gfr[(ot * 2 + 0) * 64 + l];
    bf8_t A1 = gfr[(ot * 2 + 1) * 64 + l];
#pragma unroll
    for (int pt = 0; pt < 4; ++pt) {
      f32x4 acc = {0.f, 0.f, 0.f, 0.f};
      acc = __builtin_amdgcn_mfma_f32_16x16x32_bf16(A0, Bf[pt][0], acc, 0, 0, 0);
      acc = __builtin_amdgcn_mfma_f32_16x16x32_bf16(A1, Bf[pt][1], acc, 0, 0, 0);
      const float* phn = featA + (size_t)(Pb + pt) * 64 + ot * 16 + quad * 4;
      float4 ph = *(const float4*)phn;
      uint2 psw = *(const uint2*)(featB + ((size_t)b * NPT + mve[pt]) * 128 + ot * 16 + quad * 4);
      float g0 = fmaxf(acc[0] + ph.x - bf2f((u16)(psw.x & 0xFFFF)), 0.f);
      float g1 = fmaxf(acc[1] + ph.y - bf2f((u16)(psw.x >> 16)), 0.f);
      float g2 = fmaxf(acc[2] + ph.z - bf2f((u16)(psw.y & 0xFFFF)), 0.f);
      float g3 = fmaxf(acc[3] + ph.w - bf2f((u16)(psw.y >> 16)), 0.f);
      uint2 wv = make_uint2(pkbf(g0, g1), pkbf(g2, g3));
      *(uint2*)&S16[(pt * 16 + col) * SROW + ot * 16 + quad * 4] = wv;
    }
  }
  __syncthreads();  // publish g strip (single-wave block: waitcnt fence)
  // read phase v3: lane = channel; pj loop; neighbor idx via readlane
  float mc0 = McT[l], mc1 = McT[64 + l], mc2 = McT[128 + l];
  float accv[4];
#pragma unroll 1
  for (int pj = 0; pj < 4; ++pj) {
    float4 ownq = pkb[nb0 + pj];  // uniform -> scalar path
    float gvv[16];
    float mx = -1e30f;
#pragma unroll
    for (int r = 0; r < 16; ++r) {
      gvv[r] = bf2f(S16[(pj * 16 + r) * SROW + l]);  // 128B coalesced
      mx = fmaxf(mx, gvv[r]);
    }
    float s = 0.f;
#pragma unroll
    for (int r = 0; r < 16; ++r) {
      float e = __expf(gvv[r] - mx);
      gvv[r] = e;
      s += e;
    }
    float inv = 1.0f / s;
    float acc = 0.f;
#pragma unroll
    for (int r = 0; r < 16; ++r) {
      int si = __builtin_amdgcn_readlane(idxv, pj * 16 + r);  // SGPR uniform
      float4 nbq = pkb[si];  // uniform addr -> 1 line
      float dl = fmaxf(fmaf(mc2, ownq.z - nbq.z,
                            fmaf(mc1, ownq.y - nbq.y, mc0 * (ownq.x - nbq.x))), 0.f);
      float al = bf2f(featB[((size_t)b * NPT + si) * 128 + 64 + l]);  // 128B coalesced
      acc = fmaf(gvv[r] * inv, al + dl, acc);
    }
    accv[pj] = acc;
  }
  *(float4*)(out + ((size_t)b * 64 + l) * NPT + nb0) =
      make_float4(accv[0], accv[1], accv[2], accv[3]);
}

extern "C" void kernel_launch(void* const* d_in, const int* in_sizes, int n_in,
                              void* d_out, int out_size, void* d_ws, size_t ws_size,
                              hipStream_t stream) {
  const float* features = (const float*)d_in[0];
  const float* coords = (const float*)d_in[1];
  const float* w_lin = (const float*)d_in[2];
  const float* w_t1 = (const float*)d_in[3];
  const float* w_t2 = (const float*)d_in[4];
  const float* w_g1 = (const float*)d_in[5];
  const float* w_g2 = (const float*)d_in[6];
  float* out = (float*)d_out;
  char* ws = (char*)d_ws;
  // workspace layout (~19.5 MB; part overlaps featA, consumed by refine)
  float4* pack = (float4*)ws;                   // 524288 B
  float* G = (float*)(ws + 524288);             // 16384 B
  float* Mrow = (float*)(ws + 540672);          // 768 B
  float* McT = (float*)(ws + 541440);           // 768 B
  float* wcomb = (float*)(ws + 542208);         // 49152 B
  int* idxk = (int*)(ws + 591360);              // 2 MB
  float* featA = (float*)(ws + 2688512);        // 8 MB fp32 Gphi
  u16* featB = (u16*)(ws + 11077120);           // 8 MB bf16 Gpsi|alpha
  u32* part = (u32*)(ws + 2688512);             // 3 MB (overlap, freed by refine)
  u16* GF = (u16*)(ws + 19465728);              // 8 KB bf16 A-frags

  fold1_k<<<17, 256, 0, stream>>>(w_g1, w_g2, w_t1, w_t2, G, Mrow, McT);
  fold2_k<<<64, 256, 0, stream>>>(G, w_lin, wcomb, GF);
  pack_k<<<128, 256, 0, stream>>>(coords, pack);
  knn_k<<<1024, 512, 0, stream>>>(pack, part, 0);      // quarters: attribution
  knn_k<<<1024, 512, 0, stream>>>(pack, part, 8192);
  knn_k<<<1024, 512, 0, stream>>>(pack, part, 16384);
  knn_k<<<1024, 512, 0, stream>>>(pack, part, 24576);
  refine_k<<<512, 64, 0, stream>>>(pack, part, idxk);
  feat_k<<<256, 256, 0, stream>>>(features, wcomb, featA, featB);  // reuses part region
  attn_k<<<8192, 64, 0, stream>>>(pack, idxk, featA, featB, GF, Mrow, McT, out);
}

// Round 12
// 306.572 us; speedup vs baseline: 1.1785x; 1.1785x over previous
//
#include <hip/hip_runtime.h>
#include <cstdint>

// PointTransformerLayer, MI355X. Folded-weight formulation:
//   M  = Wt2@Wt1 (64x3)          delta = relu(M . rel)
//   G  = Wg2@Wg1 (64x64)         g = relu(Gphi[n] - Gpsi[idx] + G.delta)
//   wcomb rows: [0:64)=G@W1 (phi), [64:128)=G@W2 (psi), [128:192)=Wlin (alpha)
// KNN v4: lane-parallel top-8 in regs (med3 sorted-insert), DPP min-reduce
//   merge top-24, then numpy-fp32-bit-exact re-rank (stable ties).
// R12: feat_k -> MFMA GEMM. R11 evidence: feat_k = 66us with Occ 10%
//   (1 wave/SIMD grid), VALUBusy 20%, 63MB writes for 16MB payload.
//   It is a [192x64]@[64x32768] GEMM = 0.8 GFLOP -> matrix cores.
//   fold2 prepacks wcomb as bf16 A-frags (WF, same layout as GF used by
//   attn since R8); feat wave = 16 points, 24 MFMA, fused fp32/bf16 split
//   epilogue. knn/refine/attn untouched (single-variable round).

#define NPT 8192
typedef unsigned long long u64;
typedef unsigned int u32;
typedef unsigned short u16;
typedef __attribute__((ext_vector_type(8))) short bf8_t;  // 8 bf16 (4 VGPR)
typedef __attribute__((ext_vector_type(4))) float f32x4;

__device__ __forceinline__ u16 f2bf(float x) {  // round-half-up bf16
  return (u16)((__float_as_uint(x) + 0x8000u) >> 16);
}
__device__ __forceinline__ u32 pkbf(float lo, float hi) {
  return (u32)f2bf(lo) | ((u32)f2bf(hi) << 16);
}
__device__ __forceinline__ float bf2f(u16 v) {
  return __uint_as_float((u32)v << 16);
}
__device__ __forceinline__ u32 med3u(u32 a, u32 b, u32 c) {
  u32 d;
  asm("v_med3_u32 %0, %1, %2, %3" : "=v"(d) : "v"(a), "v"(b), "v"(c));
  return d;
}
// full-wave u32 min via DPP (VALU pipe); uniform result via readlane.
__device__ __forceinline__ u32 wave_min_u32(u32 v) {
  u32 t;
  t = (u32)__builtin_amdgcn_update_dpp((int)v, (int)v, 0x111, 0xF, 0xF, false); v = min(v, t); // row_shr:1
  t = (u32)__builtin_amdgcn_update_dpp((int)v, (int)v, 0x112, 0xF, 0xF, false); v = min(v, t); // row_shr:2
  t = (u32)__builtin_amdgcn_update_dpp((int)v, (int)v, 0x114, 0xF, 0xF, false); v = min(v, t); // row_shr:4
  t = (u32)__builtin_amdgcn_update_dpp((int)v, (int)v, 0x118, 0xF, 0xF, false); v = min(v, t); // row_shr:8
  t = (u32)__builtin_amdgcn_update_dpp((int)v, (int)v, 0x142, 0xF, 0xF, false); v = min(v, t); // row_bcast:15
  t = (u32)__builtin_amdgcn_update_dpp((int)v, (int)v, 0x143, 0xF, 0xF, false); v = min(v, t); // row_bcast:31
  return (u32)__builtin_amdgcn_readlane((int)v, 63);
}

// ---------- fold1: G = Wg2@Wg1 (64x64); M = Wt2@Wt1 (64x3, row + colT) ----
__global__ __launch_bounds__(256) void fold1_k(
    const float* __restrict__ wg1, const float* __restrict__ wg2,
    const float* __restrict__ wt1, const float* __restrict__ wt2,
    float* __restrict__ G, float* __restrict__ Mrow, float* __restrict__ McT) {
  int t = blockIdx.x * 256 + threadIdx.x;
  if (t < 4096) {
    int o = t >> 6, c = t & 63;
    float acc = 0.f;
    for (int cp = 0; cp < 64; ++cp) acc = fmaf(wg2[o * 64 + cp], wg1[cp * 64 + c], acc);
    G[o * 64 + c] = acc;
  } else if (t < 4096 + 192) {
    int i = t - 4096;
    int o = i / 3, j = i - o * 3;
    float acc = 0.f;
    for (int c = 0; c < 64; ++c) acc = fmaf(wt2[o * 64 + c], wt1[c * 3 + j], acc);
    Mrow[o * 3 + j] = acc;
    McT[j * 64 + o] = acc;
  }
}

// ---------- fold2: GF (G) + WF (wcomb, 192 rows) as bf16 MFMA A-frags -----
// frag layout (16x16x32 A): element (m = lane&15, k = (lane>>4)*8 + j)
__global__ __launch_bounds__(256) void fold2_k(
    const float* __restrict__ G, const float* __restrict__ wl,
    u16* __restrict__ GF, u16* __restrict__ WF) {
  int t = blockIdx.x * 256 + threadIdx.x;  // 16384
  if (t < 12288) {
    int o = t >> 6, c = t & 63;
    float acc = 0.f;
    if (o < 64) {
      for (int cp = 0; cp < 64; ++cp) acc = fmaf(G[o * 64 + cp], wl[cp * 64 + c], acc);
    } else if (o < 128) {
      for (int cp = 0; cp < 64; ++cp) acc = fmaf(G[(o - 64) * 64 + cp], wl[(64 + cp) * 64 + c], acc);
    } else {
      acc = wl[o * 64 + c];
    }
    int ot = o >> 4, m = o & 15;
    int kh = c >> 5, q = (c >> 3) & 3, j = c & 7;
    WF[(((ot * 2 + kh) * 64) + (q * 16 + m)) * 8 + j] = f2bf(acc);
  } else {
    int i = t - 12288;
    int o = i >> 6, c = i & 63;
    int ot = o >> 4, m = o & 15;
    int kh = c >> 5, q = (c >> 3) & 3, j = c & 7;
    GF[(((ot * 2 + kh) * 64) + (q * 16 + m)) * 8 + j] = f2bf(G[o * 64 + c]);
  }
}

// ---------- pack coords as float4 (x,y,z,sq) with NP-EXACT sq -------------
__global__ __launch_bounds__(256) void pack_k(const float* __restrict__ coords,
                                              float4* __restrict__ pack) {
  int g = blockIdx.x * 256 + threadIdx.x;  // 32768
  int b = g >> 13, n = g & (NPT - 1);
  const float* c = coords + (size_t)b * 3 * NPT;
  float x = c[n], y = c[NPT + n], z = c[2 * NPT + n];
  float sq = __fadd_rn(__fadd_rn(__fmul_rn(x, x), __fmul_rn(y, y)), __fmul_rn(z, z));
  pack[g] = make_float4(x, y, z, sq);
}

// ---------- KNN v4: wave=query, per-lane reg top-8, DPP merge top-24 ------
#define QPB 8
#define CHUNK 1024
#define NQ 32768
__global__ __launch_bounds__(512) void knn_k(const float4* __restrict__ pack,
                                             u32* __restrict__ part, int qbase) {
  __shared__ float4 C[CHUNK];
  int tid = threadIdx.x;
  int w = tid >> 6, lane = tid & 63;
  int query = qbase + blockIdx.x * QPB + w;
  int b = query >> 13, n = query & (NPT - 1);
  const float4* pk = pack + (size_t)b * NPT;
  float4 q = pk[n];
  float qsq = q.w;
  u32 arr[8];
#pragma unroll
  for (int j = 0; j < 8; ++j) arr[j] = 0xFFFFFFFFu;
  for (int c0 = 0; c0 < NPT; c0 += CHUNK) {
    C[tid] = pk[c0 + tid];
    C[tid + 512] = pk[c0 + tid + 512];
    __syncthreads();
#pragma unroll 4
    for (int t = 0; t < CHUNK / 64; ++t) {
      float4 c4 = C[t * 64 + lane];
      float dot = fmaf(q.z, c4.z, fmaf(q.y, c4.y, q.x * c4.x));
      float d2 = fmaxf(fmaf(-2.f, dot, qsq + c4.w), 0.f);
      u32 key = (__float_as_uint(d2) & 0xFFFFE000u) | (u32)(c0 + t * 64 + lane);
      if (key < arr[7]) {  // sorted-insert-drop-max: 1 med3 per slot
        arr[7] = med3u(key, arr[6], arr[7]);
        arr[6] = med3u(key, arr[5], arr[6]);
        arr[5] = med3u(key, arr[4], arr[5]);
        arr[4] = med3u(key, arr[3], arr[4]);
        arr[3] = med3u(key, arr[2], arr[3]);
        arr[2] = med3u(key, arr[1], arr[2]);
        arr[1] = med3u(key, arr[0], arr[1]);
        arr[0] = min(arr[0], key);
      }
    }
    __syncthreads();
  }
  // DPP merge: pop global min 24 times (keys unique -> single owner pops)
  u32 mg = 0xFFFFFFFFu;
#pragma unroll 1
  for (int r = 0; r < 24; ++r) {
    u32 m = wave_min_u32(arr[0]);
    if (lane == r) mg = m;
    if (arr[0] == m) {  // owner pops its sorted head
      arr[0] = arr[1]; arr[1] = arr[2]; arr[2] = arr[3]; arr[3] = arr[4];
      arr[4] = arr[5]; arr[5] = arr[6]; arr[6] = arr[7]; arr[7] = 0xFFFFFFFFu;
    }
  }
  if (lane < 24) part[(size_t)lane * NQ + query] = mg;
}

// ---------- numpy-fp32-bit-exact re-rank of the 24 survivors --------------
__global__ __launch_bounds__(64) void refine_k(const float4* __restrict__ pack,
                                               const u32* __restrict__ part,
                                               int* __restrict__ idxk) {
  int g = blockIdx.x * 64 + threadIdx.x;  // 32768
  int b = g >> 13;
  const float4* pk = pack + (size_t)b * NPT;
  float4 q = pk[g & (NPT - 1)];
  float qx = q.x, qy = q.y, qz = q.z, qs = q.w;
  float bd[16];
  int bi[16];
#pragma unroll
  for (int j = 0; j < 16; ++j) { bd[j] = 1e30f; bi[j] = 0x7FFFFFFF; }
#pragma unroll 4
  for (int j = 0; j < 24; ++j) {
    int m = (int)(part[(size_t)j * NQ + g] & 0x1FFFu);
    float4 pm = pk[m];
    float dot = __fadd_rn(__fadd_rn(__fmul_rn(qx, pm.x), __fmul_rn(qy, pm.y)),
                          __fmul_rn(qz, pm.z));
    float kd = __fsub_rn(__fadd_rn(qs, pm.w), __fmul_rn(2.0f, dot));
    int ki = m;
    if (kd < bd[15] || (kd == bd[15] && ki < bi[15])) {
#pragma unroll
      for (int qq = 0; qq < 16; ++qq) {
        bool cs = (kd < bd[qq]) || (kd == bd[qq] && ki < bi[qq]);
        float td = bd[qq];
        int ti = bi[qq];
        bd[qq] = cs ? kd : td;
        bi[qq] = cs ? ki : ti;
        kd = cs ? td : kd;
        ki = cs ? ti : ki;
      }
    }
  }
#pragma unroll
  for (int j = 0; j < 16; ++j) idxk[(size_t)g * 16 + j] = bi[j];
}

// ---------- feat v2 (MFMA): [192x64]@[64x32768] -> featA fp32 / featB bf16
// Wave = 16 points (one B-tile); B[k=kh*32+quad*8+j][col=point] from
// features (64B-coalesced, bf16-packed); 12 o-tiles x 2 MFMA; epilogue
// writes rows 0-63 fp32 (featA) / 64-191 bf16 (featB).
__global__ __launch_bounds__(256) void feat_k(const float* __restrict__ features,
                                              const u16* __restrict__ WF,
                                              float* __restrict__ featA,
                                              u16* __restrict__ featB) {
  int tid = threadIdx.x;
  int w = tid >> 6, l = tid & 63;
  int quad = l >> 4, col = l & 15;
  int P = blockIdx.x * 64 + w * 16 + col;  // grid 512 x 4 waves x 16 pts
  int b = P >> 13, n = P & (NPT - 1);
  const float* fb = features + (size_t)b * 64 * NPT + n;
  const bf8_t* wfr = (const bf8_t*)WF;
  bf8_t Bf[2];
#pragma unroll
  for (int kh = 0; kh < 2; ++kh) {
    union { u32 wv[4]; bf8_t v; } ub;
#pragma unroll
    for (int j2 = 0; j2 < 4; ++j2) {
      float lo = fb[(size_t)(kh * 32 + quad * 8 + j2 * 2) * NPT];
      float hi = fb[(size_t)(kh * 32 + quad * 8 + j2 * 2 + 1) * NPT];
      ub.wv[j2] = pkbf(lo, hi);
    }
    Bf[kh] = ub.v;
  }
#pragma unroll
  for (int ot = 0; ot < 12; ++ot) {
    bf8_t A0 = wfr[(ot * 2 + 0) * 64 + l];
    bf8_t A1 = wfr[(ot * 2 + 1) * 64 + l];
    f32x4 acc = {0.f, 0.f, 0.f, 0.f};
    acc = __builtin_amdgcn_mfma_f32_16x16x32_bf16(A0, Bf[0], acc, 0, 0, 0);
    acc = __builtin_amdgcn_mfma_f32_16x16x32_bf16(A1, Bf[1], acc, 0, 0, 0);
    int gr = ot * 16 + quad * 4;  // C/D: col=lane&15, row=quad*4+reg
    if (ot < 4) {
      *(float4*)(featA + (size_t)P * 64 + gr) = make_float4(acc[0], acc[1], acc[2], acc[3]);
    } else {
      uint2 wv2 = make_uint2(pkbf(acc[0], acc[1]), pkbf(acc[2], acc[3]));
      *(uint2*)(featB + (size_t)P * 128 + (gr - 64)) = wv2;
    }
  }
}

// ---------- attention v3: MFMA core + uniform-gather read phase -----------
#define SROW 68
__global__ __launch_bounds__(64) void attn_k(
    const float4* __restrict__ pack, const int* __restrict__ idxk,
    const float* __restrict__ featA, const u16* __restrict__ featB,
    const u16* __restrict__ GF, const float* __restrict__ Mrow,
    const float* __restrict__ McT, float* __restrict__ out) {
  __shared__ u16 S16[64 * SROW];
  int l = threadIdx.x;
  int quad = l >> 4, col = l & 15;
  int Pb = blockIdx.x * 4;
  int b = Pb >> 13;
  int nb0 = Pb & (NPT - 1);
  const float4* pkb = pack + (size_t)b * NPT;
  int idxv = idxk[(size_t)Pb * 16 + l];  // lane l = (point l>>4, nbr l&15)
  int mve[4];
#pragma unroll
  for (int t = 0; t < 4; ++t) mve[t] = __shfl(idxv, t * 16 + col);
  float relx[4], rely[4], relz[4];
#pragma unroll
  for (int t = 0; t < 4; ++t) {
    float4 own = pkb[nb0 + t];
    float4 nbr = pkb[mve[t]];
    relx[t] = own.x - nbr.x; rely[t] = own.y - nbr.y; relz[t] = own.z - nbr.z;
  }
  // B-frags: u[k=kh*32+quad*8+j][p'=pt*16+col] = relu(M.rel), bf16
  bf8_t Bf[4][2];
#pragma unroll
  for (int kh = 0; kh < 2; ++kh) {
    const float* mr = Mrow + (kh * 32 + quad * 8) * 3;
    float m_[24];
#pragma unroll
    for (int i6 = 0; i6 < 6; ++i6) {
      float4 v = *(const float4*)(mr + i6 * 4);
      m_[i6 * 4] = v.x; m_[i6 * 4 + 1] = v.y; m_[i6 * 4 + 2] = v.z; m_[i6 * 4 + 3] = v.w;
    }
#pragma unroll
    for (int t = 0; t < 4; ++t) {
      float u_[8];
#pragma unroll
      for (int j = 0; j < 8; ++j)
        u_[j] = fmaxf(fmaf(m_[j * 3 + 2], relz[t],
                           fmaf(m_[j * 3 + 1], rely[t], m_[j * 3] * relx[t])), 0.f);
      union { u32 w[4]; bf8_t v; } ub;
#pragma unroll
      for (int j2 = 0; j2 < 4; ++j2) ub.w[j2] = pkbf(u_[j2 * 2], u_[j2 * 2 + 1]);
      Bf[t][kh] = ub.v;
    }
  }
  // MFMA + fused epilogue -> g (bf16) strip [pair][channel]
  const bf8_t* gfr = (const bf8_t*)GF;
#pragma unroll
  for (int ot = 0; ot < 4; ++ot) {
    bf8_t A0 = gfr[(ot * 2 + 0) * 64 + l];
    bf8_t A1 = gfr[(ot * 2 + 1) * 64 + l];
#pragma unroll
    for (int pt = 0; pt < 4; ++pt) {
      f32x4 acc = {0.f, 0.f, 0.f, 0.f};
      acc = __builtin_amdgcn_mfma_f32_16x16x32_bf16(A0, Bf[pt][0], acc, 0, 0, 0);
      acc = __builtin_amdgcn_mfma_f32_16x16x32_bf16(A1, Bf[pt][1], acc, 0, 0, 0);
      const float* phn = featA + (size_t)(Pb + pt) * 64 + ot * 16 + quad * 4;
      float4 ph = *(const float4*)phn;
      uint2 psw = *(const uint2*)(featB + ((size_t)b * NPT + mve[pt]) * 128 + ot * 16 + quad * 4);
      float g0 = fmaxf(acc[0] + ph.x - bf2f((u16)(psw.x & 0xFFFF)), 0.f);
      float g1 = fmaxf(acc[1] + ph.y - bf2f((u16)(psw.x >> 16)), 0.f);
      float g2 = fmaxf(acc[2] + ph.z - bf2f((u16)(psw.y & 0xFFFF)), 0.f);
      float g3 = fmaxf(acc[3] + ph.w - bf2f((u16)(psw.y >> 16)), 0.f);
      uint2 wv = make_uint2(pkbf(g0, g1), pkbf(g2, g3));
      *(uint2*)&S16[(pt * 16 + col) * SROW + ot * 16 + quad * 4] = wv;
    }
  }
  __syncthreads();  // publish g strip (single-wave block: waitcnt fence)
  // read phase v3: lane = channel; pj loop; neighbor idx via readlane
  float mc0 = McT[l], mc1 = McT[64 + l], mc2 = McT[128 + l];
  float accv[4];
#pragma unroll 1
  for (int pj = 0; pj < 4; ++pj) {
    float4 ownq = pkb[nb0 + pj];  // uniform -> scalar path
    float gvv[16];
    float mx = -1e30f;
#pragma unroll
    for (int r = 0; r < 16; ++r) {
      gvv[r] = bf2f(S16[(pj * 16 + r) * SROW + l]);  // 128B coalesced
      mx = fmaxf(mx, gvv[r]);
    }
    float s = 0.f;
#pragma unroll
    for (int r = 0; r < 16; ++r) {
      float e = __expf(gvv[r] - mx);
      gvv[r] = e;
      s += e;
    }
    float inv = 1.0f / s;
    float acc = 0.f;
#pragma unroll
    for (int r = 0; r < 16; ++r) {
      int si = __builtin_amdgcn_readlane(idxv, pj * 16 + r);  // SGPR uniform
      float4 nbq = pkb[si];  // uniform addr -> 1 line
      float dl = fmaxf(fmaf(mc2, ownq.z - nbq.z,
                            fmaf(mc1, ownq.y - nbq.y, mc0 * (ownq.x - nbq.x))), 0.f);
      float al = bf2f(featB[((size_t)b * NPT + si) * 128 + 64 + l]);  // 128B coalesced
      acc = fmaf(gvv[r] * inv, al + dl, acc);
    }
    accv[pj] = acc;
  }
  *(float4*)(out + ((size_t)b * 64 + l) * NPT + nb0) =
      make_float4(accv[0], accv[1], accv[2], accv[3]);
}

extern "C" void kernel_launch(void* const* d_in, const int* in_sizes, int n_in,
                              void* d_out, int out_size, void* d_ws, size_t ws_size,
                              hipStream_t stream) {
  const float* features = (const float*)d_in[0];
  const float* coords = (const float*)d_in[1];
  const float* w_lin = (const float*)d_in[2];
  const float* w_t1 = (const float*)d_in[3];
  const float* w_t2 = (const float*)d_in[4];
  const float* w_g1 = (const float*)d_in[5];
  const float* w_g2 = (const float*)d_in[6];
  float* out = (float*)d_out;
  char* ws = (char*)d_ws;
  // workspace layout (~19.5 MB; part overlaps featA, consumed by refine)
  float4* pack = (float4*)ws;                   // 524288 B
  float* G = (float*)(ws + 524288);             // 16384 B
  float* Mrow = (float*)(ws + 540672);          // 768 B
  float* McT = (float*)(ws + 541440);           // 768 B
  int* idxk = (int*)(ws + 591360);              // 2 MB
  float* featA = (float*)(ws + 2688512);        // 8 MB fp32 Gphi
  u16* featB = (u16*)(ws + 11077120);           // 8 MB bf16 Gpsi|alpha
  u32* part = (u32*)(ws + 2688512);             // 3 MB (overlap, freed by refine)
  u16* GF = (u16*)(ws + 19465728);              // 8 KB bf16 G A-frags
  u16* WF = (u16*)(ws + 19473920);              // 24 KB bf16 wcomb A-frags

  fold1_k<<<17, 256, 0, stream>>>(w_g1, w_g2, w_t1, w_t2, G, Mrow, McT);
  fold2_k<<<64, 256, 0, stream>>>(G, w_lin, GF, WF);
  pack_k<<<128, 256, 0, stream>>>(coords, pack);
  knn_k<<<1024, 512, 0, stream>>>(pack, part, 0);      // quarters: attribution
  knn_k<<<1024, 512, 0, stream>>>(pack, part, 8192);
  knn_k<<<1024, 512, 0, stream>>>(pack, part, 16384);
  knn_k<<<1024, 512, 0, stream>>>(pack, part, 24576);
  refine_k<<<512, 64, 0, stream>>>(pack, part, idxk);
  feat_k<<<512, 256, 0, stream>>>(features, WF, featA, featB);  // reuses part region
  attn_k<<<8192, 64, 0, stream>>>(pack, idxk, featA, featB, GF, Mrow, McT, out);
}